// Round 1
// baseline (1652.359 us; speedup 1.0000x reference)
//
#include <hip/hip_runtime.h>
#include <math.h>

#define BATCH 2
#define SEQ   2048
#define DIM   1024
#define HEADS 16
#define DHEAD 64
#define MROWS (BATCH * SEQ)   // 4096

// ---------------- GEMM: C[M,N] = A[M,K] @ W[K,N] + bias[N] ------------------
// BM=BN=64, BK=16, 256 threads, 4x4 per thread. All dims divisible by tiles.
__global__ __launch_bounds__(256) void gemm_bias_kernel(
    const float* __restrict__ A, const float* __restrict__ W,
    const float* __restrict__ bias, float* __restrict__ C,
    int M, int N, int K) {
  __shared__ float sA[16][64];
  __shared__ float sB[16][64];
  const int tid  = threadIdx.x;
  const int row0 = blockIdx.y * 64;
  const int col0 = blockIdx.x * 64;
  const int ty = tid >> 4;   // 0..15
  const int tx = tid & 15;   // 0..15

  float acc[4][4] = {};

  for (int k0 = 0; k0 < K; k0 += 16) {
    // A tile: 64 rows x 16 k  (idx: m = idx>>4, kk = idx&15)
    #pragma unroll
    for (int it = 0; it < 4; ++it) {
      int idx = tid + it * 256;
      int m  = idx >> 4;
      int kk = idx & 15;
      sA[kk][m] = A[(size_t)(row0 + m) * K + (k0 + kk)];
    }
    // W tile: 16 k x 64 n (idx: kk = idx>>6, n = idx&63)
    #pragma unroll
    for (int it = 0; it < 4; ++it) {
      int idx = tid + it * 256;
      int kk = idx >> 6;
      int n  = idx & 63;
      sB[kk][n] = W[(size_t)(k0 + kk) * N + (col0 + n)];
    }
    __syncthreads();
    #pragma unroll
    for (int kk = 0; kk < 16; ++kk) {
      float a[4], b[4];
      #pragma unroll
      for (int i = 0; i < 4; ++i) a[i] = sA[kk][ty * 4 + i];
      #pragma unroll
      for (int j = 0; j < 4; ++j) b[j] = sB[kk][tx * 4 + j];
      #pragma unroll
      for (int i = 0; i < 4; ++i)
        #pragma unroll
        for (int j = 0; j < 4; ++j)
          acc[i][j] += a[i] * b[j];
    }
    __syncthreads();
  }

  #pragma unroll
  for (int i = 0; i < 4; ++i) {
    int r = row0 + ty * 4 + i;
    #pragma unroll
    for (int j = 0; j < 4; ++j) {
      int c = col0 + tx * 4 + j;
      C[(size_t)r * N + c] = acc[i][j] + bias[c];
    }
  }
}

// ---------------- Flash attention (fp32), one block per (b, h, 64-row qtile)
__global__ __launch_bounds__(256) void attn_kernel(
    const float* __restrict__ q, const float* __restrict__ k,
    const float* __restrict__ v, float* __restrict__ o) {
  __shared__ float sQ[64][DHEAD + 1];
  __shared__ float sK[64][DHEAD + 1];
  __shared__ float sV[64][DHEAD + 1];
  __shared__ float sS[64][65];
  __shared__ float sM[64], sL[64], sC[64];

  const int tid = threadIdx.x;
  const int qt = blockIdx.x;   // 0..31
  const int h  = blockIdx.y;   // 0..15
  const int b  = blockIdx.z;   // 0..1
  const size_t base = (size_t)b * SEQ * DIM + (size_t)h * DHEAD;
  const int q0 = qt * 64;

  // load Q tile, scaled by 1/sqrt(DH) = 1/8
  #pragma unroll
  for (int it = 0; it < 16; ++it) {
    int idx = tid + it * 256;
    int r = idx >> 6, d = idx & 63;
    sQ[r][d] = q[base + (size_t)(q0 + r) * DIM + d] * 0.125f;
  }
  if (tid < 64) { sM[tid] = -1e30f; sL[tid] = 0.0f; }

  const int ty = tid >> 4;   // row group 0..15
  const int tx = tid & 15;   // col group 0..15
  float acc[4][4] = {};

  for (int t = 0; t < SEQ / 64; ++t) {
    __syncthreads();   // protect sK/sV still being read from prev iteration
    #pragma unroll
    for (int it = 0; it < 16; ++it) {
      int idx = tid + it * 256;
      int r = idx >> 6, d = idx & 63;
      sK[r][d] = k[base + (size_t)(t * 64 + r) * DIM + d];
      sV[r][d] = v[base + (size_t)(t * 64 + r) * DIM + d];
    }
    __syncthreads();

    // S = Q K^T  (each thread 4x4 of the 64x64)
    float s[4][4] = {};
    #pragma unroll 8
    for (int d = 0; d < DHEAD; ++d) {
      float a[4], bb[4];
      #pragma unroll
      for (int i = 0; i < 4; ++i) a[i] = sQ[ty * 4 + i][d];
      #pragma unroll
      for (int j = 0; j < 4; ++j) bb[j] = sK[tx * 4 + j][d];
      #pragma unroll
      for (int i = 0; i < 4; ++i)
        #pragma unroll
        for (int j = 0; j < 4; ++j)
          s[i][j] += a[i] * bb[j];
    }
    #pragma unroll
    for (int i = 0; i < 4; ++i)
      #pragma unroll
      for (int j = 0; j < 4; ++j)
        sS[ty * 4 + i][tx * 4 + j] = s[i][j];
    __syncthreads();

    // online softmax per row (64 rows, one thread each)
    if (tid < 64) {
      float m_old = sM[tid];
      float m_new = m_old;
      #pragma unroll 8
      for (int j = 0; j < 64; ++j) m_new = fmaxf(m_new, sS[tid][j]);
      float c = __expf(m_old - m_new);
      float sum = 0.0f;
      #pragma unroll 8
      for (int j = 0; j < 64; ++j) {
        float p = __expf(sS[tid][j] - m_new);
        sS[tid][j] = p;
        sum += p;
      }
      sL[tid] = sL[tid] * c + sum;
      sM[tid] = m_new;
      sC[tid] = c;
    }
    __syncthreads();

    // O = O*c + P @ V
    #pragma unroll
    for (int i = 0; i < 4; ++i) {
      float c = sC[ty * 4 + i];
      #pragma unroll
      for (int j = 0; j < 4; ++j) acc[i][j] *= c;
    }
    #pragma unroll 8
    for (int j2 = 0; j2 < 64; ++j2) {
      float vv[4];
      #pragma unroll
      for (int j = 0; j < 4; ++j) vv[j] = sV[j2][tx * 4 + j];
      #pragma unroll
      for (int i = 0; i < 4; ++i) {
        float p = sS[ty * 4 + i][j2];
        #pragma unroll
        for (int j = 0; j < 4; ++j) acc[i][j] += p * vv[j];
      }
    }
  }

  // epilogue: divide by l, write out
  #pragma unroll
  for (int i = 0; i < 4; ++i) {
    float inv = 1.0f / sL[ty * 4 + i];
    #pragma unroll
    for (int j = 0; j < 4; ++j) {
      o[base + (size_t)(q0 + ty * 4 + i) * DIM + tx * 4 + j] = acc[i][j] * inv;
    }
  }
}

extern "C" void kernel_launch(void* const* d_in, const int* in_sizes, int n_in,
                              void* d_out, int out_size, void* d_ws, size_t ws_size,
                              hipStream_t stream) {
  const float* query = (const float*)d_in[0];
  const float* key_i = (const float*)d_in[1];
  const float* val_i = (const float*)d_in[2];
  const float* Wq = (const float*)d_in[3];
  const float* bq = (const float*)d_in[4];
  const float* Wk = (const float*)d_in[5];
  const float* bk = (const float*)d_in[6];
  const float* Wv = (const float*)d_in[7];
  const float* bv = (const float*)d_in[8];
  const float* Wo = (const float*)d_in[9];
  const float* bo = (const float*)d_in[10];

  const size_t mat = (size_t)MROWS * DIM;   // 4096*1024 floats
  float* qb = (float*)d_ws;
  float* kb = qb + mat;
  float* vb = kb + mat;
  float* ab = vb + mat;

  dim3 gblk(DIM / 64, MROWS / 64);   // (16, 64)
  gemm_bias_kernel<<<gblk, 256, 0, stream>>>(query, Wq, bq, qb, MROWS, DIM, DIM);
  gemm_bias_kernel<<<gblk, 256, 0, stream>>>(key_i, Wk, bk, kb, MROWS, DIM, DIM);
  gemm_bias_kernel<<<gblk, 256, 0, stream>>>(val_i, Wv, bv, vb, MROWS, DIM, DIM);

  attn_kernel<<<dim3(SEQ / 64, HEADS, BATCH), 256, 0, stream>>>(qb, kb, vb, ab);

  gemm_bias_kernel<<<gblk, 256, 0, stream>>>(ab, Wo, bo, (float*)d_out, MROWS, DIM, DIM);
}

// Round 2
// 364.379 us; speedup vs baseline: 4.5347x; 4.5347x over previous
//
#include <hip/hip_runtime.h>

#define BATCH 2
#define SEQ   2048
#define DIM   1024
#define HEADS 16
#define DHEAD 64
#define MROWS (BATCH*SEQ)

typedef __attribute__((ext_vector_type(8))) short short8;
typedef __attribute__((ext_vector_type(4))) float floatx4;

static __device__ __forceinline__ unsigned short f2bf(float x){
  union { float f; unsigned int u; } c; c.f = x;
  unsigned int r = c.u + 0x7fffu + ((c.u >> 16) & 1u);   // RTNE
  return (unsigned short)(r >> 16);
}

static __device__ __forceinline__ void gload16(const void* g, void* l){
  __builtin_amdgcn_global_load_lds(
      (const __attribute__((address_space(1))) unsigned int*)g,
      (__attribute__((address_space(3))) unsigned int*)l, 16, 0, 0);
}

// ---------------- fp32 -> bf16 (8 elems/thread) ----------------
__global__ __launch_bounds__(256) void cvt_kernel(const float* __restrict__ src,
                                                  unsigned short* __restrict__ dst,
                                                  int n8){
  int i = blockIdx.x * 256 + threadIdx.x;
  if (i >= n8) return;
  const float4* sp = (const float4*)src + (size_t)i * 2;
  float4 a = sp[0], b = sp[1];
  uint4 o;
  o.x = (unsigned)f2bf(a.x) | ((unsigned)f2bf(a.y) << 16);
  o.y = (unsigned)f2bf(a.z) | ((unsigned)f2bf(a.w) << 16);
  o.z = (unsigned)f2bf(b.x) | ((unsigned)f2bf(b.y) << 16);
  o.w = (unsigned)f2bf(b.z) | ((unsigned)f2bf(b.w) << 16);
  *((uint4*)dst + i) = o;
}

// ---------------- W[K][N] fp32 -> Wt[N][K] bf16 ----------------
__global__ __launch_bounds__(256) void twt_kernel(const float* __restrict__ W,
                                                  unsigned short* __restrict__ Wt){
  __shared__ float t[32][33];
  int n0 = blockIdx.x * 32, k0 = blockIdx.y * 32;
  int c = threadIdx.x & 31, r4 = threadIdx.x >> 5;
  #pragma unroll
  for (int it = 0; it < 4; ++it){
    int r = r4 + it * 8;
    t[r][c] = W[(size_t)(k0 + r) * DIM + n0 + c];
  }
  __syncthreads();
  #pragma unroll
  for (int it = 0; it < 4; ++it){
    int r = r4 + it * 8;
    Wt[(size_t)(n0 + r) * DIM + k0 + c] = f2bf(t[c][r]);
  }
}

// ---------------- NT GEMM: C[i][j] = sum_k A[i][k] * B[j][k] ----------------
// A: [I][1024] bf16 row-major, B: [J][1024] bf16 row-major.
// mode 0: bf16 C[i*DIM+j] + bias[j]
// mode 1: bf16 vT: ((j>>11)*DIM + i)*SEQ + (j&2047), + bias[i]
// mode 2: f32  C[i*DIM+j] + bias[j]
__global__ __launch_bounds__(256) void gemm_nt_kernel(
    const unsigned short* __restrict__ A, const unsigned short* __restrict__ B,
    const float* __restrict__ bias, void* __restrict__ Cout, int mode){
  // LDS: A chunk-major [8][128][8] bf16 = 16KB at 0; B same at 16384.
  __shared__ char smem[32768];
  const int tid  = threadIdx.x;
  const int lane = tid & 63;
  const int w    = tid >> 6;          // 0..3
  const int wr   = w >> 1, wc = w & 1;
  const int lr   = lane & 15, lc = lane >> 4;
  const int i0   = blockIdx.y * 128;
  const int j0   = blockIdx.x * 128;

  floatx4 acc[4][4];
  #pragma unroll
  for (int m = 0; m < 4; ++m)
    #pragma unroll
    for (int n = 0; n < 4; ++n)
      acc[m][n] = (floatx4){0.f, 0.f, 0.f, 0.f};

  // wave w stages chunks {w, w+4} of each tile, rows lane and 64+lane
  const unsigned short* gA = A + (size_t)(i0 + lane) * DIM + w * 8;
  const unsigned short* gB = B + (size_t)(j0 + lane) * DIM + w * 8;
  char* lA = smem + w * 2048;
  char* lB = smem + 16384 + w * 2048;

  for (int k0 = 0; k0 < DIM; k0 += 64){
    gload16(gA + k0,                        lA);
    gload16(gA + k0 + (size_t)64 * DIM,     lA + 1024);
    gload16(gA + k0 + 32,                   lA + 8192);
    gload16(gA + k0 + 32 + (size_t)64 * DIM, lA + 8192 + 1024);
    gload16(gB + k0,                        lB);
    gload16(gB + k0 + (size_t)64 * DIM,     lB + 1024);
    gload16(gB + k0 + 32,                   lB + 8192);
    gload16(gB + k0 + 32 + (size_t)64 * DIM, lB + 8192 + 1024);
    __syncthreads();   // drains vmcnt -> tiles resident
    #pragma unroll
    for (int ks = 0; ks < 2; ++ks){
      short8 af[4], bfr[4];
      #pragma unroll
      for (int m = 0; m < 4; ++m)
        af[m] = *(const short8*)(smem + (ks * 4 + lc) * 2048 + (wr * 64 + m * 16 + lr) * 16);
      #pragma unroll
      for (int n = 0; n < 4; ++n)
        bfr[n] = *(const short8*)(smem + 16384 + (ks * 4 + lc) * 2048 + (wc * 64 + n * 16 + lr) * 16);
      #pragma unroll
      for (int m = 0; m < 4; ++m)
        #pragma unroll
        for (int n = 0; n < 4; ++n)
          acc[m][n] = __builtin_amdgcn_mfma_f32_16x16x32_bf16(af[m], bfr[n], acc[m][n], 0, 0, 0);
    }
    __syncthreads();
  }

  #pragma unroll
  for (int m = 0; m < 4; ++m){
    #pragma unroll
    for (int r = 0; r < 4; ++r){
      int i = i0 + wr * 64 + m * 16 + lc * 4 + r;
      #pragma unroll
      for (int n = 0; n < 4; ++n){
        int j = j0 + wc * 64 + n * 16 + lr;
        float v = acc[m][n][r];
        if (mode == 0){
          ((unsigned short*)Cout)[(size_t)i * DIM + j] = f2bf(v + bias[j]);
        } else if (mode == 1){
          ((unsigned short*)Cout)[((size_t)(j >> 11) * DIM + i) * SEQ + (j & 2047)] = f2bf(v + bias[i]);
        } else {
          ((float*)Cout)[(size_t)i * DIM + j] = v + bias[j];
        }
      }
    }
  }
}

// ---------------- Flash attention, bf16 MFMA, S^T = K*Q^T trick -------------
// qb,kb: [B*S][DIM] bf16 (head h at cols h*64..); vt: [B][DIM][S] bf16; ao same as qb.
__global__ __launch_bounds__(256) void attn_kernel(
    const unsigned short* __restrict__ qb, const unsigned short* __restrict__ kb,
    const unsigned short* __restrict__ vt, unsigned short* __restrict__ ao){
  // LDS: K tile chunk-major [8][64][8] = 8KB at 0, V tile (from vT) same at 8192.
  __shared__ char smem[16384];
  const int tid  = threadIdx.x;
  const int lane = tid & 63;
  const int w    = tid >> 6;          // wave: q-rows q0 + w*16 .. +16
  const int lr   = lane & 15, lc = lane >> 4;
  const int qt = blockIdx.x, h = blockIdx.y, b = blockIdx.z;
  const int q0 = qt * 64;

  // Q fragment (acts as B-operand of S^T = K*Q^T): row = q0+w*16+lr, d = lc*8+e (+32)
  const unsigned short* qrow = qb + (size_t)(b * SEQ + q0 + w * 16 + lr) * DIM + h * DHEAD + lc * 8;
  short8 qf0 = *(const short8*)(qrow);
  short8 qf1 = *(const short8*)(qrow + 32);

  float om = -1e30f, ol = 0.f;
  floatx4 oacc[4];
  #pragma unroll
  for (int dt = 0; dt < 4; ++dt) oacc[dt] = (floatx4){0.f, 0.f, 0.f, 0.f};

  const unsigned short* gK = kb + (size_t)(b * SEQ + lane) * DIM + h * DHEAD;
  const unsigned short* gV = vt + (size_t)(b * DIM + h * DHEAD + lane) * SEQ;

  for (int t = 0; t < SEQ / 64; ++t){
    // stage K tile (d-chunks) and V tile (j-chunks), 4 gload16 per wave
    gload16(gK + (size_t)t * 64 * DIM + (2 * w) * 8,     smem + (2 * w) * 1024);
    gload16(gK + (size_t)t * 64 * DIM + (2 * w + 1) * 8, smem + (2 * w + 1) * 1024);
    gload16(gV + t * 64 + (2 * w) * 8,                   smem + 8192 + (2 * w) * 1024);
    gload16(gV + t * 64 + (2 * w + 1) * 8,               smem + 8192 + (2 * w + 1) * 1024);
    __syncthreads();

    // S^T tile: thread holds S^T[j = jt*16 + lc*4 + r][i = lr]
    floatx4 st[4];
    #pragma unroll
    for (int jt = 0; jt < 4; ++jt) st[jt] = (floatx4){0.f, 0.f, 0.f, 0.f};
    #pragma unroll
    for (int jt = 0; jt < 4; ++jt){
      short8 kf0 = *(const short8*)(smem + lc * 1024       + (jt * 16 + lr) * 16);
      short8 kf1 = *(const short8*)(smem + (4 + lc) * 1024 + (jt * 16 + lr) * 16);
      st[jt] = __builtin_amdgcn_mfma_f32_16x16x32_bf16(kf0, qf0, st[jt], 0, 0, 0);
      st[jt] = __builtin_amdgcn_mfma_f32_16x16x32_bf16(kf1, qf1, st[jt], 0, 0, 0);
    }

    float sv[16];
    #pragma unroll
    for (int jt = 0; jt < 4; ++jt)
      #pragma unroll
      for (int r = 0; r < 4; ++r)
        sv[jt * 4 + r] = st[jt][r] * 0.125f;    // 1/sqrt(64)

    float tmax = sv[0];
    #pragma unroll
    for (int idx = 1; idx < 16; ++idx) tmax = fmaxf(tmax, sv[idx]);
    tmax = fmaxf(tmax, __shfl_xor(tmax, 16, 64));
    tmax = fmaxf(tmax, __shfl_xor(tmax, 32, 64));
    float mnew = fmaxf(om, tmax);
    float cc = __expf(om - mnew);
    float ps = 0.f;
    unsigned int plo[4], phi[4];
    #pragma unroll
    for (int jt = 0; jt < 4; ++jt){
      float p0 = __expf(sv[jt * 4 + 0] - mnew);
      float p1 = __expf(sv[jt * 4 + 1] - mnew);
      float p2 = __expf(sv[jt * 4 + 2] - mnew);
      float p3 = __expf(sv[jt * 4 + 3] - mnew);
      ps += (p0 + p1) + (p2 + p3);
      plo[jt] = (unsigned)f2bf(p0) | ((unsigned)f2bf(p1) << 16);
      phi[jt] = (unsigned)f2bf(p2) | ((unsigned)f2bf(p3) << 16);
    }
    ps += __shfl_xor(ps, 16, 64);
    ps += __shfl_xor(ps, 32, 64);
    ol = ol * cc + ps;
    om = mnew;
    #pragma unroll
    for (int dt = 0; dt < 4; ++dt) oacc[dt] *= cc;

    // PV: O^T[d][i] += sum_j V^T[d][j] P^T[j][i]; j-permutation
    // pi(ks,lc,e) = ks*32 + (e>>2)*16 + lc*4 + (e&3) shared by A(V) and B(P),
    // which makes the P fragment exactly this thread's own registers.
    #pragma unroll
    for (int ks = 0; ks < 2; ++ks){
      union { short8 s; unsigned int u[4]; } pb;
      pb.u[0] = plo[2 * ks];     pb.u[1] = phi[2 * ks];
      pb.u[2] = plo[2 * ks + 1]; pb.u[3] = phi[2 * ks + 1];
      #pragma unroll
      for (int dt = 0; dt < 4; ++dt){
        union { short8 s; uint2 hh[2]; } vf;
        const char* vbase = smem + 8192 + (ks * 4 + (lc >> 1)) * 1024 + (dt * 16 + lr) * 16 + (lc & 1) * 8;
        vf.hh[0] = *(const uint2*)(vbase);
        vf.hh[1] = *(const uint2*)(vbase + 2048);
        oacc[dt] = __builtin_amdgcn_mfma_f32_16x16x32_bf16(vf.s, pb.s, oacc[dt], 0, 0, 0);
      }
    }
    __syncthreads();
  }

  float inv = 1.0f / ol;
  size_t obase = (size_t)(b * SEQ + q0 + w * 16 + lr) * DIM + h * DHEAD;
  #pragma unroll
  for (int dt = 0; dt < 4; ++dt){
    uint2 val;
    val.x = (unsigned)f2bf(oacc[dt][0] * inv) | ((unsigned)f2bf(oacc[dt][1] * inv) << 16);
    val.y = (unsigned)f2bf(oacc[dt][2] * inv) | ((unsigned)f2bf(oacc[dt][3] * inv) << 16);
    *(uint2*)(ao + obase + dt * 16 + lc * 4) = val;
  }
}

extern "C" void kernel_launch(void* const* d_in, const int* in_sizes, int n_in,
                              void* d_out, int out_size, void* d_ws, size_t ws_size,
                              hipStream_t stream){
  const float* query = (const float*)d_in[0];
  const float* key_i = (const float*)d_in[1];
  const float* val_i = (const float*)d_in[2];
  const float* Wq = (const float*)d_in[3];
  const float* bq = (const float*)d_in[4];
  const float* Wk = (const float*)d_in[5];
  const float* bk = (const float*)d_in[6];
  const float* Wv = (const float*)d_in[7];
  const float* bv = (const float*)d_in[8];
  const float* Wo = (const float*)d_in[9];
  const float* bo = (const float*)d_in[10];

  char* p = (char*)d_ws;
  const size_t MB = 1024 * 1024;
  unsigned short* xq  = (unsigned short*)(p + 0 * MB);
  unsigned short* xk  = (unsigned short*)(p + 8 * MB);
  unsigned short* xv  = (unsigned short*)(p + 16 * MB);
  unsigned short* wqt = (unsigned short*)(p + 24 * MB);
  unsigned short* wkt = (unsigned short*)(p + 26 * MB);
  unsigned short* wvt = (unsigned short*)(p + 28 * MB);
  unsigned short* wot = (unsigned short*)(p + 30 * MB);
  unsigned short* qb  = (unsigned short*)(p + 32 * MB);
  unsigned short* kb  = (unsigned short*)(p + 40 * MB);
  unsigned short* vt  = (unsigned short*)(p + 48 * MB);
  unsigned short* aob = (unsigned short*)(p + 56 * MB);

  int n8 = MROWS * DIM / 8;   // 524288
  cvt_kernel<<<n8 / 256, 256, 0, stream>>>(query, xq, n8);
  cvt_kernel<<<n8 / 256, 256, 0, stream>>>(key_i, xk, n8);
  cvt_kernel<<<n8 / 256, 256, 0, stream>>>(val_i, xv, n8);
  dim3 tg(32, 32);
  twt_kernel<<<tg, 256, 0, stream>>>(Wq, wqt);
  twt_kernel<<<tg, 256, 0, stream>>>(Wk, wkt);
  twt_kernel<<<tg, 256, 0, stream>>>(Wv, wvt);
  twt_kernel<<<tg, 256, 0, stream>>>(Wo, wot);

  // q = x@Wq + bq ; k = x@Wk + bk   (bf16 out, row-major)
  gemm_nt_kernel<<<dim3(8, 32), 256, 0, stream>>>(xq, wqt, bq, qb, 0);
  gemm_nt_kernel<<<dim3(8, 32), 256, 0, stream>>>(xk, wkt, bk, kb, 0);
  // v^T: A = Wv^T (I=1024 d-rows), B = xv (J=4096 rows) -> vT[b][d][s]
  gemm_nt_kernel<<<dim3(32, 8), 256, 0, stream>>>(wvt, xv, bv, vt, 1);

  attn_kernel<<<dim3(SEQ / 64, HEADS, BATCH), 256, 0, stream>>>(qb, kb, vt, aob);

  // out = ao@Wo + bo (fp32 out)
  gemm_nt_kernel<<<dim3(8, 32), 256, 0, stream>>>(aob, wot, bo, (float*)d_out, 2);
}

// Round 4
// 278.933 us; speedup vs baseline: 5.9239x; 1.3063x over previous
//
#include <hip/hip_runtime.h>

#define BATCH 2
#define SEQ   2048
#define DIM   1024
#define HEADS 16
#define DHEAD 64
#define MROWS (BATCH*SEQ)

// 1/sqrt(DHEAD) * log2(e): folded into q projection; softmax runs in exp2 domain
#define QSCALE 0.1803368801111204f

typedef __attribute__((ext_vector_type(8))) short short8;
typedef __attribute__((ext_vector_type(4))) float floatx4;

static __device__ __forceinline__ unsigned short f2bf(float x){
  union { float f; unsigned int u; } c; c.f = x;
  unsigned int r = c.u + 0x7fffu + ((c.u >> 16) & 1u);   // RTNE
  return (unsigned short)(r >> 16);
}

static __device__ __forceinline__ float exp2_hw(float x){
  float r;
  asm("v_exp_f32 %0, %1" : "=v"(r) : "v"(x));
  return r;
}

static __device__ __forceinline__ unsigned int cvtpk_bf16(float a, float b){
  unsigned int u;
  asm("v_cvt_pk_bf16_f32 %0, %1, %2" : "=v"(u) : "v"(a), "v"(b));
  return u;
}

static __device__ __forceinline__ void gload16(const void* g, void* l){
  __builtin_amdgcn_global_load_lds(
      (const __attribute__((address_space(1))) unsigned int*)g,
      (__attribute__((address_space(3))) unsigned int*)l, 16, 0, 0);
}

// ---------------- fp32 -> bf16, 3 tensors in one launch ----------------
__global__ __launch_bounds__(256) void cvt_all_kernel(
    const float* __restrict__ s0, const float* __restrict__ s1,
    const float* __restrict__ s2, unsigned short* __restrict__ d0,
    unsigned short* __restrict__ d1, unsigned short* __restrict__ d2){
  const float* src = (blockIdx.y == 0) ? s0 : (blockIdx.y == 1) ? s1 : s2;
  unsigned short* dst = (blockIdx.y == 0) ? d0 : (blockIdx.y == 1) ? d1 : d2;
  int i = blockIdx.x * 256 + threadIdx.x;
  const float4* sp = (const float4*)src + (size_t)i * 2;
  float4 a = sp[0], b = sp[1];
  uint4 o;
  o.x = cvtpk_bf16(a.x, a.y);
  o.y = cvtpk_bf16(a.z, a.w);
  o.z = cvtpk_bf16(b.x, b.y);
  o.w = cvtpk_bf16(b.z, b.w);
  *((uint4*)dst + i) = o;
}

// ---------------- W[K][N] fp32 -> Wt[N][K] bf16, 4 weights in one launch ----
__global__ __launch_bounds__(256) void twt_all_kernel(
    const float* __restrict__ w0, const float* __restrict__ w1,
    const float* __restrict__ w2, const float* __restrict__ w3,
    unsigned short* __restrict__ t0, unsigned short* __restrict__ t1,
    unsigned short* __restrict__ t2, unsigned short* __restrict__ t3){
  const int z = blockIdx.z;
  const float* W = (z == 0) ? w0 : (z == 1) ? w1 : (z == 2) ? w2 : w3;
  unsigned short* Wt = (z == 0) ? t0 : (z == 1) ? t1 : (z == 2) ? t2 : t3;
  __shared__ float t[32][33];
  int n0 = blockIdx.x * 32, k0 = blockIdx.y * 32;
  int c = threadIdx.x & 31, r4 = threadIdx.x >> 5;
  #pragma unroll
  for (int it = 0; it < 4; ++it){
    int r = r4 + it * 8;
    t[r][c] = W[(size_t)(k0 + r) * DIM + n0 + c];
  }
  __syncthreads();
  #pragma unroll
  for (int it = 0; it < 4; ++it){
    int r = r4 + it * 8;
    Wt[(size_t)(n0 + r) * DIM + k0 + c] = f2bf(t[c][r]);
  }
}

// ------ merged projection NT GEMM: C[i][j] = sum_k A[i][k]*B[j][k] ---------
// blockIdx.y selects {q, k, v}; 768 blocks total -> 3 blocks/CU.
// z=0: qb = (x@Wq + bq) * QSCALE  (bf16)
// z=1: kb =  x@Wk + bk            (bf16)
// z=2: vT = (Wv^T x^T + bv)       (bf16, [b][d][s] layout)
__global__ __launch_bounds__(256, 3) void proj_gemm_kernel(
    const unsigned short* __restrict__ xq, const unsigned short* __restrict__ xk,
    const unsigned short* __restrict__ xv, const unsigned short* __restrict__ wqt,
    const unsigned short* __restrict__ wkt, const unsigned short* __restrict__ wvt,
    const float* __restrict__ bq, const float* __restrict__ bk,
    const float* __restrict__ bv, unsigned short* __restrict__ qb,
    unsigned short* __restrict__ kb, unsigned short* __restrict__ vt){
  __shared__ char smem[32768];
  const int z = blockIdx.y;
  const unsigned short* A = (z == 0) ? xq  : (z == 1) ? xk  : wvt;
  const unsigned short* B = (z == 0) ? wqt : (z == 1) ? wkt : xv;
  const float* bias        = (z == 0) ? bq  : (z == 1) ? bk  : bv;

  const int bx = blockIdx.x;
  const int i0 = (z < 2) ? ((bx >> 3) * 128) : ((bx & 7) * 128);
  const int j0 = (z < 2) ? ((bx & 7) * 128) : ((bx >> 3) * 128);

  const int tid  = threadIdx.x;
  const int lane = tid & 63;
  const int w    = tid >> 6;
  const int wr   = w >> 1, wc = w & 1;
  const int lr   = lane & 15, lc = lane >> 4;

  floatx4 acc[4][4];
  #pragma unroll
  for (int m = 0; m < 4; ++m)
    #pragma unroll
    for (int n = 0; n < 4; ++n)
      acc[m][n] = (floatx4){0.f, 0.f, 0.f, 0.f};

  const unsigned short* gA = A + (size_t)(i0 + lane) * DIM + w * 8;
  const unsigned short* gB = B + (size_t)(j0 + lane) * DIM + w * 8;
  char* lA = smem + w * 2048;
  char* lB = smem + 16384 + w * 2048;

  for (int k0 = 0; k0 < DIM; k0 += 64){
    gload16(gA + k0,                         lA);
    gload16(gA + k0 + (size_t)64 * DIM,      lA + 1024);
    gload16(gA + k0 + 32,                    lA + 8192);
    gload16(gA + k0 + 32 + (size_t)64 * DIM, lA + 8192 + 1024);
    gload16(gB + k0,                         lB);
    gload16(gB + k0 + (size_t)64 * DIM,      lB + 1024);
    gload16(gB + k0 + 32,                    lB + 8192);
    gload16(gB + k0 + 32 + (size_t)64 * DIM, lB + 8192 + 1024);
    __syncthreads();
    #pragma unroll
    for (int ks = 0; ks < 2; ++ks){
      short8 af[4], bfr[4];
      #pragma unroll
      for (int m = 0; m < 4; ++m)
        af[m] = *(const short8*)(smem + (ks * 4 + lc) * 2048 + (wr * 64 + m * 16 + lr) * 16);
      #pragma unroll
      for (int n = 0; n < 4; ++n)
        bfr[n] = *(const short8*)(smem + 16384 + (ks * 4 + lc) * 2048 + (wc * 64 + n * 16 + lr) * 16);
      #pragma unroll
      for (int m = 0; m < 4; ++m)
        #pragma unroll
        for (int n = 0; n < 4; ++n)
          acc[m][n] = __builtin_amdgcn_mfma_f32_16x16x32_bf16(af[m], bfr[n], acc[m][n], 0, 0, 0);
    }
    __syncthreads();
  }

  #pragma unroll
  for (int m = 0; m < 4; ++m){
    #pragma unroll
    for (int r = 0; r < 4; ++r){
      int i = i0 + wr * 64 + m * 16 + lc * 4 + r;
      #pragma unroll
      for (int n = 0; n < 4; ++n){
        int j = j0 + wc * 64 + n * 16 + lr;
        float v = acc[m][n][r];
        if (z == 0){
          qb[(size_t)i * DIM + j] = f2bf((v + bias[j]) * QSCALE);
        } else if (z == 1){
          kb[(size_t)i * DIM + j] = f2bf(v + bias[j]);
        } else {
          vt[((size_t)(j >> 11) * DIM + i) * SEQ + (j & 2047)] = f2bf(v + bias[i]);
        }
      }
    }
  }
}

// ------ out-proj NT GEMM, 128x64 tile (512 blocks -> 2/CU), fp32 out -------
__global__ __launch_bounds__(256, 2) void gemm_out_kernel(
    const unsigned short* __restrict__ A, const unsigned short* __restrict__ B,
    const float* __restrict__ bias, float* __restrict__ C){
  __shared__ char smem[24576];
  const int tid  = threadIdx.x;
  const int lane = tid & 63;
  const int w    = tid >> 6;
  const int wr   = w >> 1, wc = w & 1;
  const int lr   = lane & 15, lc = lane >> 4;
  const int i0   = blockIdx.y * 128;
  const int j0   = blockIdx.x * 64;

  floatx4 acc[4][2];
  #pragma unroll
  for (int m = 0; m < 4; ++m)
    #pragma unroll
    for (int n = 0; n < 2; ++n)
      acc[m][n] = (floatx4){0.f, 0.f, 0.f, 0.f};

  const unsigned short* gA = A + (size_t)(i0 + lane) * DIM + w * 8;
  const unsigned short* gB = B + (size_t)(j0 + lane) * DIM + w * 8;
  char* lA = smem + w * 2048;

  for (int k0 = 0; k0 < DIM; k0 += 64){
    gload16(gA + k0,                         lA);
    gload16(gA + k0 + (size_t)64 * DIM,      lA + 1024);
    gload16(gA + k0 + 32,                    lA + 8192);
    gload16(gA + k0 + 32 + (size_t)64 * DIM, lA + 8192 + 1024);
    gload16(gB + k0,        smem + 16384 + w * 1024);
    gload16(gB + k0 + 32,   smem + 16384 + (w + 4) * 1024);
    __syncthreads();
    #pragma unroll
    for (int ks = 0; ks < 2; ++ks){
      short8 af[4], bfr[2];
      #pragma unroll
      for (int m = 0; m < 4; ++m)
        af[m] = *(const short8*)(smem + (ks * 4 + lc) * 2048 + (wr * 64 + m * 16 + lr) * 16);
      #pragma unroll
      for (int n = 0; n < 2; ++n)
        bfr[n] = *(const short8*)(smem + 16384 + (ks * 4 + lc) * 1024 + (wc * 32 + n * 16 + lr) * 16);
      #pragma unroll
      for (int m = 0; m < 4; ++m)
        #pragma unroll
        for (int n = 0; n < 2; ++n)
          acc[m][n] = __builtin_amdgcn_mfma_f32_16x16x32_bf16(af[m], bfr[n], acc[m][n], 0, 0, 0);
    }
    __syncthreads();
  }

  #pragma unroll
  for (int m = 0; m < 4; ++m){
    #pragma unroll
    for (int r = 0; r < 4; ++r){
      int i = i0 + wr * 64 + m * 16 + lc * 4 + r;
      #pragma unroll
      for (int n = 0; n < 2; ++n){
        int j = j0 + wc * 32 + n * 16 + lr;
        C[(size_t)i * DIM + j] = acc[m][n][r] + bias[j];
      }
    }
  }
}

// ---------------- Flash attention, exp2-domain softmax ----------------------
__global__ __launch_bounds__(256, 4) void attn_kernel(
    const unsigned short* __restrict__ qb, const unsigned short* __restrict__ kb,
    const unsigned short* __restrict__ vt, unsigned short* __restrict__ ao){
  __shared__ char smem[16384];
  const int tid  = threadIdx.x;
  const int lane = tid & 63;
  const int w    = tid >> 6;
  const int lr   = lane & 15, lc = lane >> 4;
  const int qt = blockIdx.x, h = blockIdx.y, b = blockIdx.z;
  const int q0 = qt * 64;

  const unsigned short* qrow = qb + (size_t)(b * SEQ + q0 + w * 16 + lr) * DIM + h * DHEAD + lc * 8;
  short8 qf0 = *(const short8*)(qrow);
  short8 qf1 = *(const short8*)(qrow + 32);

  float om = -1e30f, ol = 0.f;
  floatx4 oacc[4];
  #pragma unroll
  for (int dt = 0; dt < 4; ++dt) oacc[dt] = (floatx4){0.f, 0.f, 0.f, 0.f};

  const unsigned short* gK = kb + (size_t)(b * SEQ + lane) * DIM + h * DHEAD;
  const unsigned short* gV = vt + (size_t)(b * DIM + h * DHEAD + lane) * SEQ;

  for (int t = 0; t < SEQ / 64; ++t){
    gload16(gK + (size_t)t * 64 * DIM + (2 * w) * 8,     smem + (2 * w) * 1024);
    gload16(gK + (size_t)t * 64 * DIM + (2 * w + 1) * 8, smem + (2 * w + 1) * 1024);
    gload16(gV + t * 64 + (2 * w) * 8,                   smem + 8192 + (2 * w) * 1024);
    gload16(gV + t * 64 + (2 * w + 1) * 8,               smem + 8192 + (2 * w + 1) * 1024);
    __syncthreads();

    // S^T tile (already in log2 domain: q pre-scaled by 1/8*log2e)
    floatx4 st[4];
    #pragma unroll
    for (int jt = 0; jt < 4; ++jt) st[jt] = (floatx4){0.f, 0.f, 0.f, 0.f};
    #pragma unroll
    for (int jt = 0; jt < 4; ++jt){
      short8 kf0 = *(const short8*)(smem + lc * 1024       + (jt * 16 + lr) * 16);
      short8 kf1 = *(const short8*)(smem + (4 + lc) * 1024 + (jt * 16 + lr) * 16);
      st[jt] = __builtin_amdgcn_mfma_f32_16x16x32_bf16(kf0, qf0, st[jt], 0, 0, 0);
      st[jt] = __builtin_amdgcn_mfma_f32_16x16x32_bf16(kf1, qf1, st[jt], 0, 0, 0);
    }

    float tmax = st[0][0];
    #pragma unroll
    for (int jt = 0; jt < 4; ++jt)
      #pragma unroll
      for (int r = 0; r < 4; ++r)
        tmax = fmaxf(tmax, st[jt][r]);
    tmax = fmaxf(tmax, __shfl_xor(tmax, 16, 64));
    tmax = fmaxf(tmax, __shfl_xor(tmax, 32, 64));

    // defer-max (T13): only rescale when the running max grew by > 8 (log2)
    if (!__all(tmax <= om + 8.0f)){
      float mnew = fmaxf(om, tmax);
      float cc = exp2_hw(om - mnew);
      ol *= cc;
      #pragma unroll
      for (int dt = 0; dt < 4; ++dt) oacc[dt] *= cc;
      om = mnew;
    }

    float ps = 0.f;
    unsigned int plo[4], phi[4];
    #pragma unroll
    for (int jt = 0; jt < 4; ++jt){
      float p0 = exp2_hw(st[jt][0] - om);
      float p1 = exp2_hw(st[jt][1] - om);
      float p2 = exp2_hw(st[jt][2] - om);
      float p3 = exp2_hw(st[jt][3] - om);
      ps += (p0 + p1) + (p2 + p3);
      plo[jt] = cvtpk_bf16(p0, p1);
      phi[jt] = cvtpk_bf16(p2, p3);
    }
    ps += __shfl_xor(ps, 16, 64);
    ps += __shfl_xor(ps, 32, 64);
    ol += ps;

    #pragma unroll
    for (int ks = 0; ks < 2; ++ks){
      union { short8 s; unsigned int u[4]; } pb;
      pb.u[0] = plo[2 * ks];     pb.u[1] = phi[2 * ks];
      pb.u[2] = plo[2 * ks + 1]; pb.u[3] = phi[2 * ks + 1];
      #pragma unroll
      for (int dt = 0; dt < 4; ++dt){
        union { short8 s; uint2 hh[2]; } vf;
        const char* vbase = smem + 8192 + (ks * 4 + (lc >> 1)) * 1024 + (dt * 16 + lr) * 16 + (lc & 1) * 8;
        vf.hh[0] = *(const uint2*)(vbase);
        vf.hh[1] = *(const uint2*)(vbase + 2048);
        oacc[dt] = __builtin_amdgcn_mfma_f32_16x16x32_bf16(vf.s, pb.s, oacc[dt], 0, 0, 0);
      }
    }
    __syncthreads();
  }

  float inv = 1.0f / ol;
  size_t obase = (size_t)(b * SEQ + q0 + w * 16 + lr) * DIM + h * DHEAD;
  #pragma unroll
  for (int dt = 0; dt < 4; ++dt){
    uint2 val;
    val.x = cvtpk_bf16(oacc[dt][0] * inv, oacc[dt][1] * inv);
    val.y = cvtpk_bf16(oacc[dt][2] * inv, oacc[dt][3] * inv);
    *(uint2*)(ao + obase + dt * 16 + lc * 4) = val;
  }
}

extern "C" void kernel_launch(void* const* d_in, const int* in_sizes, int n_in,
                              void* d_out, int out_size, void* d_ws, size_t ws_size,
                              hipStream_t stream){
  const float* query = (const float*)d_in[0];
  const float* key_i = (const float*)d_in[1];
  const float* val_i = (const float*)d_in[2];
  const float* Wq = (const float*)d_in[3];
  const float* bq = (const float*)d_in[4];
  const float* Wk = (const float*)d_in[5];
  const float* bk = (const float*)d_in[6];
  const float* Wv = (const float*)d_in[7];
  const float* bv = (const float*)d_in[8];
  const float* Wo = (const float*)d_in[9];
  const float* bo = (const float*)d_in[10];

  char* p = (char*)d_ws;
  const size_t MB = 1024 * 1024;
  unsigned short* xq  = (unsigned short*)(p + 0 * MB);
  unsigned short* xk  = (unsigned short*)(p + 8 * MB);
  unsigned short* xv  = (unsigned short*)(p + 16 * MB);
  unsigned short* wqt = (unsigned short*)(p + 24 * MB);
  unsigned short* wkt = (unsigned short*)(p + 26 * MB);
  unsigned short* wvt = (unsigned short*)(p + 28 * MB);
  unsigned short* wot = (unsigned short*)(p + 30 * MB);
  unsigned short* qb  = (unsigned short*)(p + 32 * MB);
  unsigned short* kb  = (unsigned short*)(p + 40 * MB);
  unsigned short* vt  = (unsigned short*)(p + 48 * MB);
  unsigned short* aob = (unsigned short*)(p + 56 * MB);

  cvt_all_kernel<<<dim3(2048, 3), 256, 0, stream>>>(query, key_i, val_i, xq, xk, xv);
  twt_all_kernel<<<dim3(32, 32, 4), 256, 0, stream>>>(Wq, Wk, Wv, Wo, wqt, wkt, wvt, wot);

  proj_gemm_kernel<<<dim3(256, 3), 256, 0, stream>>>(
      xq, xk, xv, wqt, wkt, wvt, bq, bk, bv, qb, kb, vt);

  attn_kernel<<<dim3(SEQ / 64, HEADS, BATCH), 256, 0, stream>>>(qb, kb, vt, aob);

  gemm_out_kernel<<<dim3(16, 32), 256, 0, stream>>>(aob, wot, bo, (float*)d_out);
}